// Round 6
// baseline (688.038 us; speedup 1.0000x reference)
//
#include <hip/hip_runtime.h>
#include <stdint.h>

// MixtureOfSoftmaxes: B=1024, H=4, D=256, V=100000
// out[b,v] = sum_h pi[b,h] * softmax_v(proj[b,h,:]·emb[v,:])
// No-max softmax (|logits| < ~3):
//   pass C: part[vb][m] = sum_{v in vb} exp(l[m,v]); reduce -> w = pi/s
//   pass D: out[b,v] = sum_h w[m]*exp(l[m,v])
// R6: 256x256 tile, BK=64, counted-vmcnt pipeline (stage k+1 at top of k-step k,
// vmcnt(8) leaves next stage in flight, 2 barriers/k-step), bijective XCD swizzle
// so each XCD owns a contiguous v-range (embB read from HBM ~once).

#define VOCAB 100000
#define NVB 391      // v-blocks of 256 (covers 100096)
#define VPAD 100096

typedef __attribute__((ext_vector_type(8))) short short8;
typedef __attribute__((ext_vector_type(4))) float f32x4;

__device__ __forceinline__ short f2bf(float f) {
  uint32_t u = __float_as_uint(f);
  u = (u + 0x7FFFu + ((u >> 16) & 1u)) >> 16;
  return (short)u;
}

#define VMCNT(n) asm volatile("s_waitcnt vmcnt(" #n ")" ::: "memory")
#define LGKM0()  asm volatile("s_waitcnt lgkmcnt(0)" ::: "memory")
#define SCHED0() __builtin_amdgcn_sched_barrier(0)
#define BAR()    __builtin_amdgcn_s_barrier()

// ---------------- kernel 1: proj = tanh(x @ proj_mat^T) -> bf16 [4096 x 256] ----
__global__ __launch_bounds__(256) void proj_kernel(const float* __restrict__ x,
                                                   const float* __restrict__ pm,
                                                   short* __restrict__ projA) {
  __shared__ float xs[64][36];
  __shared__ float ps[64][36];
  const int tid = threadIdx.x;
  const int tx = tid & 15, ty = tid >> 4;
  const int m0 = blockIdx.y * 64, n0 = blockIdx.x * 64;
  float acc[4][4];
#pragma unroll
  for (int i = 0; i < 4; i++)
#pragma unroll
    for (int j = 0; j < 4; j++) acc[i][j] = 0.f;

  for (int k0 = 0; k0 < 256; k0 += 32) {
    const int r = tid >> 2, c = (tid & 3) * 8;
    *(float4*)&xs[r][c]     = *(const float4*)&x[(m0 + r) * 256 + k0 + c];
    *(float4*)&xs[r][c + 4] = *(const float4*)&x[(m0 + r) * 256 + k0 + c + 4];
    *(float4*)&ps[r][c]     = *(const float4*)&pm[(n0 + r) * 256 + k0 + c];
    *(float4*)&ps[r][c + 4] = *(const float4*)&pm[(n0 + r) * 256 + k0 + c + 4];
    __syncthreads();
#pragma unroll
    for (int kk = 0; kk < 32; kk += 4) {
      float4 xa[4], pb[4];
#pragma unroll
      for (int i = 0; i < 4; i++) xa[i] = *(const float4*)&xs[ty * 4 + i][kk];
#pragma unroll
      for (int j = 0; j < 4; j++) pb[j] = *(const float4*)&ps[tx * 4 + j][kk];
#pragma unroll
      for (int i = 0; i < 4; i++)
#pragma unroll
        for (int j = 0; j < 4; j++)
          acc[i][j] += xa[i].x * pb[j].x + xa[i].y * pb[j].y +
                       xa[i].z * pb[j].z + xa[i].w * pb[j].w;
    }
    __syncthreads();
  }
#pragma unroll
  for (int i = 0; i < 4; i++)
#pragma unroll
    for (int j = 0; j < 4; j++)
      projA[(size_t)(m0 + ty * 4 + i) * 1024 + (n0 + tx * 4 + j)] = f2bf(tanhf(acc[i][j]));
}

// ---------------- kernel 2: pi = softmax(x @ mix_mat^T)  [1024 x 4] --------------
__global__ __launch_bounds__(256) void pi_kernel(const float* __restrict__ x,
                                                 const float* __restrict__ mm,
                                                 float* __restrict__ pi) {
  int b = blockIdx.x * 256 + threadIdx.x;
  if (b >= 1024) return;
  float acc[4] = {0.f, 0.f, 0.f, 0.f};
  for (int k = 0; k < 256; k += 4) {
    float4 xv = *(const float4*)&x[(size_t)b * 256 + k];
#pragma unroll
    for (int h = 0; h < 4; h++) {
      float4 mv = *(const float4*)&mm[h * 256 + k];
      acc[h] += xv.x * mv.x + xv.y * mv.y + xv.z * mv.z + xv.w * mv.w;
    }
  }
  float mx = fmaxf(fmaxf(acc[0], acc[1]), fmaxf(acc[2], acc[3]));
  float e[4], ssum = 0.f;
#pragma unroll
  for (int h = 0; h < 4; h++) { e[h] = __expf(acc[h] - mx); ssum += e[h]; }
#pragma unroll
  for (int h = 0; h < 4; h++) pi[b * 4 + h] = e[h] / ssum;
}

// ---------------- kernel 3: embB = bf16(emb), zero-padded to VPAD rows -----------
__global__ __launch_bounds__(256) void embB_kernel(const float* __restrict__ emb,
                                                   short* __restrict__ embB) {
  size_t i = ((size_t)blockIdx.x * 256 + threadIdx.x) * 8;  // element index
  size_t row = i >> 8;
  short8 b8;
  if (row < VOCAB) {
    float4 f0 = *(const float4*)&emb[i];
    float4 f1 = *(const float4*)&emb[i + 4];
    b8[0] = f2bf(f0.x); b8[1] = f2bf(f0.y); b8[2] = f2bf(f0.z); b8[3] = f2bf(f0.w);
    b8[4] = f2bf(f1.x); b8[5] = f2bf(f1.y); b8[6] = f2bf(f1.z); b8[7] = f2bf(f1.w);
  } else {
#pragma unroll
    for (int j = 0; j < 8; ++j) b8[j] = 0;
  }
  *(short8*)&embB[i] = b8;
}

// ---------------- big GEMM: 256x256 tile, BK=64, counted-vmcnt pipeline ---------
// LDS buffer b (0/1) at b*65536: A-tile 256x64 bf16 (32KB) at +0, B-tile at +32768.
// Row = 128 B = 8 chunks of 16 B; chunk swizzle: LDS chunk c holds global chunk
// c ^ (row & 7) (source pre-swizzled, LDS dest linear).

// stage K-step kt (8 global_load_lds: 4 A + 4 B) into buffer `buf`
__device__ __forceinline__ void stage_AB(const char* gA, const char* gB, char* sm,
                                         int buf, int kt, int wid) {
#pragma unroll
  for (int h = 0; h < 2; ++h)
#pragma unroll
    for (int j = 0; j < 2; ++j) {
      __builtin_amdgcn_global_load_lds(
          (const __attribute__((address_space(1))) void*)(gA + kt * 128 + h * 65536 + j * 32768),
          (__attribute__((address_space(3))) void*)(sm + buf * 65536 + h * 16384 + j * 8192 + wid * 1024),
          16, 0, 0);
      __builtin_amdgcn_global_load_lds(
          (const __attribute__((address_space(1))) void*)(gB + kt * 128 + h * 65536 + j * 32768),
          (__attribute__((address_space(3))) void*)(sm + buf * 65536 + 32768 + h * 16384 + j * 8192 + wid * 1024),
          16, 0, 0);
    }
}

template <int KT>
__device__ __forceinline__ void k_step(char* sm, const char* gA, const char* gB, int wid,
                                       f32x4 (&acc)[8][4], int aK0, int aK1, int bK0, int bK1) {
  constexpr int CB = (KT & 1) * 65536;
  // top: stage k+1 into other buffer (all waves' reads of it ended at prev barrier),
  // then wait only for THIS k-step's stage (prev issued) -> 1-k-step cover.
  if (KT < 3) {
    stage_AB(gA, gB, sm, (KT + 1) & 1, KT + 1, wid);
    SCHED0();
    VMCNT(8);
  } else {
    SCHED0();
    VMCNT(0);
  }
  BAR();  // buffer CB fully staged for all waves
  SCHED0();

  short8 b[4][2], a0[4][2], a1[4][2];
#pragma unroll
  for (int j = 0; j < 4; ++j) {
    b[j][0] = *(const short8*)(sm + CB + bK0 + j * 2048);
    b[j][1] = *(const short8*)(sm + CB + bK1 + j * 2048);
  }
#pragma unroll
  for (int i = 0; i < 4; ++i) {
    a0[i][0] = *(const short8*)(sm + CB + aK0 + i * 2048);
    a0[i][1] = *(const short8*)(sm + CB + aK1 + i * 2048);
  }
  // cluster 1: m-half 0 (32 MFMA); a1 reads interleave under it
  __builtin_amdgcn_s_setprio(1);
#pragma unroll
  for (int ks = 0; ks < 2; ++ks)
#pragma unroll
    for (int i = 0; i < 4; ++i)
#pragma unroll
      for (int j = 0; j < 4; ++j)
        acc[i][j] = __builtin_amdgcn_mfma_f32_16x16x32_bf16(a0[i][ks], b[j][ks], acc[i][j], 0, 0, 0);
  __builtin_amdgcn_s_setprio(0);
#pragma unroll
  for (int i = 0; i < 4; ++i) {
    a1[i][0] = *(const short8*)(sm + CB + aK0 + (4 + i) * 2048);
    a1[i][1] = *(const short8*)(sm + CB + aK1 + (4 + i) * 2048);
  }
  LGKM0();   // all our LDS reads of CB complete
  SCHED0();  // keep reads above the barrier
  BAR();     // all waves done reading CB -> next k-step may restage it
  SCHED0();
  // cluster 2: m-half 1 (pure-register; overlaps next k-step's stage + ds_reads)
  __builtin_amdgcn_s_setprio(1);
#pragma unroll
  for (int ks = 0; ks < 2; ++ks)
#pragma unroll
    for (int i = 0; i < 4; ++i)
#pragma unroll
      for (int j = 0; j < 4; ++j)
        acc[4 + i][j] =
            __builtin_amdgcn_mfma_f32_16x16x32_bf16(a1[i][ks], b[j][ks], acc[4 + i][j], 0, 0, 0);
  __builtin_amdgcn_s_setprio(0);
}

template <int MODE>
__global__ __launch_bounds__(512, 2) void mos_gemm8(const short* __restrict__ projA_s,
                                                    const short* __restrict__ embB_s,
                                                    const float* __restrict__ w,
                                                    float* __restrict__ part,
                                                    float* __restrict__ out) {
  __shared__ __align__(16) char sm[131072];
  const int tid = threadIdx.x;
  const int lane = tid & 63, wid = tid >> 6;
  const int wr = wid >> 2, wc = wid & 3;  // 2 (m) x 4 (v) wave grid
  const int l15 = lane & 15, l4 = lane >> 4;

  // bijective XCD swizzle: 6256 = 8 * 782; each XCD owns ~49 consecutive v-blocks,
  // walking all 16 m-blocks per v-block -> L2 set = projA (2MB) + ~2 embB tiles.
  const int id = blockIdx.x;
  const int sw = (id & 7) * 782 + (id >> 3);
  const int vb = sw >> 4, mb = sw & 15;
  const int m0 = mb * 256;
  const int v0 = vb * 256;

  // per-thread staging sources (pre-swizzled so linear LDS dest = swizzled layout)
  const int cxor = ((tid & 7) ^ ((tid >> 3) & 7)) * 16;
  const char* gA = (const char*)projA_s + (size_t)(m0 + (tid >> 3)) * 512 + cxor;
  const char* gB = (const char*)embB_s + (size_t)(v0 + (tid >> 3)) * 512 + cxor;

  // per-lane ds-read offsets (within buffer 0)
  const int sA = l15 & 7;
  const int aK0 = (wr * 128 + l15) * 128 + ((l4 ^ sA) << 4);
  const int aK1 = (wr * 128 + l15) * 128 + (((4 + l4) ^ sA) << 4);
  const int bK0 = 32768 + (wc * 64 + l15) * 128 + ((l4 ^ sA) << 4);
  const int bK1 = 32768 + (wc * 64 + l15) * 128 + (((4 + l4) ^ sA) << 4);

  f32x4 acc[8][4];
#pragma unroll
  for (int i = 0; i < 8; ++i)
#pragma unroll
    for (int j = 0; j < 4; ++j) acc[i][j] = (f32x4){0.f, 0.f, 0.f, 0.f};

  // prologue: stage K-step 0 only; k_step<0> stages k1 then waits vmcnt(8) (=k0)
  stage_AB(gA, gB, sm, 0, 0, wid);
  SCHED0();

  k_step<0>(sm, gA, gB, wid, acc, aK0, aK1, bK0, bK1);
  k_step<1>(sm, gA, gB, wid, acc, aK0, aK1, bK0, bK1);
  k_step<2>(sm, gA, gB, wid, acc, aK0, aK1, bK0, bK1);
  k_step<3>(sm, gA, gB, wid, acc, aK0, aK1, bK0, bK1);

  if (MODE == 0) {
    // partial softmax denominators over this block's 256 v-cols
#pragma unroll
    for (int mi = 0; mi < 8; ++mi) {
      float p[4] = {0.f, 0.f, 0.f, 0.f};
#pragma unroll
      for (int ni = 0; ni < 4; ++ni) {
        int v = v0 + wc * 64 + ni * 16 + l15;
        bool ok = v < VOCAB;
#pragma unroll
        for (int r = 0; r < 4; ++r) {
          float e = __expf(acc[mi][ni][r]);
          p[r] += ok ? e : 0.f;
        }
      }
#pragma unroll
      for (int r = 0; r < 4; ++r) {
        p[r] += __shfl_xor(p[r], 1, 64);
        p[r] += __shfl_xor(p[r], 2, 64);
        p[r] += __shfl_xor(p[r], 4, 64);
        p[r] += __shfl_xor(p[r], 8, 64);
      }
      if (l15 == 0) {
        float4 pv = {p[0], p[1], p[2], p[3]};
        *(float4*)(sm + (wc * 256 + wr * 128 + mi * 16 + l4 * 4) * 4) = pv;
      }
    }
    __syncthreads();
    if (tid < 256) {
      const float* rf = (const float*)sm;
      float ssum = rf[tid] + rf[256 + tid] + rf[512 + tid] + rf[768 + tid];
      part[(size_t)vb * 4096 + m0 + tid] = ssum;
    }
  } else {
    // out[b, v] = sum_h w[m]*exp(l);  acc regs r=0..3 are the 4 heads of one b
#pragma unroll
    for (int mi = 0; mi < 8; ++mi) {
      int mbase = m0 + wr * 128 + mi * 16;
      float4 wv = *(const float4*)&w[mbase + l4 * 4];
      size_t brow = (size_t)(mbase >> 2) + l4;
#pragma unroll
      for (int ni = 0; ni < 4; ++ni) {
        int v = v0 + wc * 64 + ni * 16 + l15;
        float val = wv.x * __expf(acc[mi][ni][0]) + wv.y * __expf(acc[mi][ni][1]) +
                    wv.z * __expf(acc[mi][ni][2]) + wv.w * __expf(acc[mi][ni][3]);
        if (v < VOCAB) out[brow * VOCAB + v] = val;
      }
    }
  }
}

// ---------------- reduce partials + w = pi / s ----------------------------------
__global__ __launch_bounds__(256) void reduce_w(const float* __restrict__ part,
                                                const float* __restrict__ pi,
                                                float* __restrict__ w) {
  int m = blockIdx.x * 256 + threadIdx.x;  // 0..4095
  float sum = 0.f;
  for (int c = 0; c < NVB; ++c) sum += part[(size_t)c * 4096 + m];
  w[m] = pi[m] / sum;
}

extern "C" void kernel_launch(void* const* d_in, const int* in_sizes, int n_in,
                              void* d_out, int out_size, void* d_ws, size_t ws_size,
                              hipStream_t stream) {
  const float* x        = (const float*)d_in[0];
  const float* proj_mat = (const float*)d_in[1];
  const float* mix_mat  = (const float*)d_in[2];
  const float* emb      = (const float*)d_in[3];
  float* out = (float*)d_out;

  char* ws = (char*)d_ws;
  short* projA = (short*)ws;                          // bf16 [4096][256] = 2 MB
  float* pi    = (float*)(ws + (2u << 20));           // [4096]
  float* w     = (float*)(ws + (2u << 20) + 16384);   // [4096]
  short* embB  = (short*)(ws + (4u << 20));           // bf16 [100096][256] = 48.9 MB
  float* part  = (float*)(ws + (4u << 20) + (size_t)VPAD * 512);  // [391][4096] = 6.4 MB

  dim3 g1(16, 16);
  proj_kernel<<<g1, 256, 0, stream>>>(x, proj_mat, projA);
  pi_kernel<<<4, 256, 0, stream>>>(x, mix_mat, pi);
  embB_kernel<<<VPAD / 8, 256, 0, stream>>>(emb, embB);

  mos_gemm8<0><<<16 * NVB, 512, 0, stream>>>(projA, embB, nullptr, part, nullptr);
  reduce_w<<<16, 256, 0, stream>>>(part, pi, w);
  mos_gemm8<1><<<16 * NVB, 512, 0, stream>>>(projA, embB, w, nullptr, out);
}